// Round 4
// baseline (603.387 us; speedup 1.0000x reference)
//
#include <hip/hip_runtime.h>
#include <hip/hip_bf16.h>

// DeepseekV3MoEToA2AAdapter: B=2,S=1024 -> T=2048 tokens, H=1024, E=8, I=1408, top-2.
// All tensor I/O is fp32 (per reference dtypes). GEMMs run bf16 MFMA internally.
#define T_TOK 2048
#define HDIM  1024
#define NEXP  8
#define IDIM  1408
#define TOPK  2

#define BM 128
#define BN 128
#define BK 32
#define KPAD 40   // LDS leading-dim pad (bf16 elems): 80 B rows, 16B aligned
#define MT_SLOTS 16

typedef __attribute__((ext_vector_type(8))) short bf16x8;
typedef __attribute__((ext_vector_type(4))) float f32x4;

static __device__ __forceinline__ unsigned short f2bf(float f) {
    union { float f; unsigned u; } a; a.f = f;
    return (unsigned short)((a.u + 0x7fffu + ((a.u >> 16) & 1u)) >> 16);
}

// ---------------------------------------------------------------- router ----
// One wave per token, fp64 accumulation (robust top-2 ordering vs np fp32).
// softmax -> top2 -> renorm  ==  w1 = 1/(1+exp(l2-l1)), w2 = 1-w1.
__global__ __launch_bounds__(256) void router_kernel(
    const float* __restrict__ x,        // [T, H]
    const float* __restrict__ rw,       // [H, E]
    int*   __restrict__ counts,         // [E]
    int*   __restrict__ tok_list,       // [E][T]
    float* __restrict__ wgt_list,       // [E][T]
    int*   __restrict__ row_list)       // [E][T]  pair row id (2t / 2t+1)
{
    const int wave = (blockIdx.x * blockDim.x + threadIdx.x) >> 6;
    const int lane = threadIdx.x & 63;
    if (wave >= T_TOK) return;
    const int t = wave;

    float xr[16];
    const float* xp = x + (size_t)t * HDIM;
#pragma unroll
    for (int i = 0; i < 16; ++i) xr[i] = xp[lane + 64 * i];

    double logits[NEXP];
#pragma unroll
    for (int e = 0; e < NEXP; ++e) {
        double s = 0.0;
#pragma unroll
        for (int i = 0; i < 16; ++i) {
            const int j = lane + 64 * i;
            s += (double)xr[i] * (double)rw[j * NEXP + e];
        }
#pragma unroll
        for (int off = 32; off > 0; off >>= 1)
            s += __shfl_down(s, off, 64);
        logits[e] = s;   // valid on lane 0
    }

    if (lane == 0) {
        int e1 = 0;
        for (int e = 1; e < NEXP; ++e) if (logits[e] > logits[e1]) e1 = e;
        int e2 = -1;
        for (int e = 0; e < NEXP; ++e) {
            if (e == e1) continue;
            if (e2 < 0 || logits[e] > logits[e2]) e2 = e;
        }
        const double w1 = 1.0 / (1.0 + exp(logits[e2] - logits[e1]));
        const double w2 = 1.0 - w1;
        int p1 = atomicAdd(&counts[e1], 1);
        tok_list[e1 * T_TOK + p1] = t;
        wgt_list[e1 * T_TOK + p1] = (float)w1;
        row_list[e1 * T_TOK + p1] = 2 * t;
        int p2 = atomicAdd(&counts[e2], 1);
        tok_list[e2 * T_TOK + p2] = t;
        wgt_list[e2 * T_TOK + p2] = (float)w2;
        row_list[e2 * T_TOK + p2] = 2 * t + 1;
    }
}

// -------------------------------------------------- fused gate+up GEMM -----
// A = x rows gathered by tok_list (fp32 -> bf16 in staging), K = HDIM.
// B = gate_w and up_w [K, IDIM] fp32 -> bf16, transposed to LDS [n][k].
// Epilogue: act[pair_row][n] = bf16( silu(g+gb) * (u+ub) ).
__global__ __launch_bounds__(256) void gateup_kernel(
    const float* __restrict__ x,
    const float* __restrict__ gw, const float* __restrict__ uw,
    const float* __restrict__ gb, const float* __restrict__ ub,
    const int* __restrict__ counts,
    const int* __restrict__ tok_list,
    const int* __restrict__ row_list,
    unsigned short* __restrict__ act)          // [2T, IDIM] bf16
{
    const int e  = blockIdx.x >> 4;
    const int mt = blockIdx.x & 15;
    const int n_e = counts[e];
    const int m0 = mt * BM;
    if (m0 >= n_e) return;
    const int n0 = blockIdx.y * BN;

    const float* gwp = gw + (size_t)e * HDIM * IDIM;
    const float* uwp = uw + (size_t)e * HDIM * IDIM;
    const float* gbp = gb + (size_t)e * IDIM;
    const float* ubp = ub + (size_t)e * IDIM;

    __shared__ unsigned short As[BM][KPAD];
    __shared__ unsigned short Bg[BN][KPAD];
    __shared__ unsigned short Bu[BN][KPAD];
    __shared__ int gr_lds[BM];
    __shared__ int or_lds[BM];

    const int tid = threadIdx.x;
    const int base = e * T_TOK;
    if (tid < BM) {
        const int m = m0 + tid;
        int g = -1, o = -1;
        if (m < n_e) { g = tok_list[base + m]; o = row_list[base + m]; }
        gr_lds[tid] = g; or_lds[tid] = o;
    }
    __syncthreads();

    const int ar = tid >> 1;
    const int ac = (tid & 1) * 16;          // 16 fp32 -> 16 bf16 per thread
    const int arow = gr_lds[ar];
    const float* ap = (arow >= 0) ? (x + (size_t)arow * HDIM) : x;
    const int bn = (tid & 31) * 4;
    const int bk = (tid >> 5) * 4;

    const int wv = tid >> 6, lane = tid & 63;
    const int wm = (wv & 1) * 64, wn = (wv >> 1) * 64;
    const int l16 = lane & 15, quad = lane >> 4;

    f32x4 accg[4][4], accu[4][4];
    const f32x4 zero = {0.0f, 0.0f, 0.0f, 0.0f};
#pragma unroll
    for (int i = 0; i < 4; ++i)
#pragma unroll
        for (int j = 0; j < 4; ++j) { accg[i][j] = zero; accu[i][j] = zero; }

    for (int k0 = 0; k0 < HDIM; k0 += BK) {
        // A tile: fp32 -> bf16
        {
            ushort4 o0 = {0,0,0,0}, o1 = {0,0,0,0}, o2 = {0,0,0,0}, o3 = {0,0,0,0};
            if (arow >= 0) {
                const float4 v0 = *(const float4*)(ap + k0 + ac);
                const float4 v1 = *(const float4*)(ap + k0 + ac + 4);
                const float4 v2 = *(const float4*)(ap + k0 + ac + 8);
                const float4 v3 = *(const float4*)(ap + k0 + ac + 12);
                o0.x = f2bf(v0.x); o0.y = f2bf(v0.y); o0.z = f2bf(v0.z); o0.w = f2bf(v0.w);
                o1.x = f2bf(v1.x); o1.y = f2bf(v1.y); o1.z = f2bf(v1.z); o1.w = f2bf(v1.w);
                o2.x = f2bf(v2.x); o2.y = f2bf(v2.y); o2.z = f2bf(v2.z); o2.w = f2bf(v2.w);
                o3.x = f2bf(v3.x); o3.y = f2bf(v3.y); o3.z = f2bf(v3.z); o3.w = f2bf(v3.w);
            }
            *(ushort4*)&As[ar][ac]      = o0;
            *(ushort4*)&As[ar][ac + 4]  = o1;
            *(ushort4*)&As[ar][ac + 8]  = o2;
            *(ushort4*)&As[ar][ac + 12] = o3;
        }
        // B tiles: fp32 -> bf16, transpose into [n][k]
        {
            const size_t boff = (size_t)(k0 + bk) * IDIM + n0 + bn;
            const float4 g0 = *(const float4*)(gwp + boff);
            const float4 g1 = *(const float4*)(gwp + boff + IDIM);
            const float4 g2 = *(const float4*)(gwp + boff + 2 * IDIM);
            const float4 g3 = *(const float4*)(gwp + boff + 3 * IDIM);
            ushort4 w;
            w.x = f2bf(g0.x); w.y = f2bf(g1.x); w.z = f2bf(g2.x); w.w = f2bf(g3.x);
            *(ushort4*)&Bg[bn + 0][bk] = w;
            w.x = f2bf(g0.y); w.y = f2bf(g1.y); w.z = f2bf(g2.y); w.w = f2bf(g3.y);
            *(ushort4*)&Bg[bn + 1][bk] = w;
            w.x = f2bf(g0.z); w.y = f2bf(g1.z); w.z = f2bf(g2.z); w.w = f2bf(g3.z);
            *(ushort4*)&Bg[bn + 2][bk] = w;
            w.x = f2bf(g0.w); w.y = f2bf(g1.w); w.z = f2bf(g2.w); w.w = f2bf(g3.w);
            *(ushort4*)&Bg[bn + 3][bk] = w;
            const float4 u0 = *(const float4*)(uwp + boff);
            const float4 u1 = *(const float4*)(uwp + boff + IDIM);
            const float4 u2 = *(const float4*)(uwp + boff + 2 * IDIM);
            const float4 u3 = *(const float4*)(uwp + boff + 3 * IDIM);
            w.x = f2bf(u0.x); w.y = f2bf(u1.x); w.z = f2bf(u2.x); w.w = f2bf(u3.x);
            *(ushort4*)&Bu[bn + 0][bk] = w;
            w.x = f2bf(u0.y); w.y = f2bf(u1.y); w.z = f2bf(u2.y); w.w = f2bf(u3.y);
            *(ushort4*)&Bu[bn + 1][bk] = w;
            w.x = f2bf(u0.z); w.y = f2bf(u1.z); w.z = f2bf(u2.z); w.w = f2bf(u3.z);
            *(ushort4*)&Bu[bn + 2][bk] = w;
            w.x = f2bf(u0.w); w.y = f2bf(u1.w); w.z = f2bf(u2.w); w.w = f2bf(u3.w);
            *(ushort4*)&Bu[bn + 3][bk] = w;
        }
        __syncthreads();

        bf16x8 af[4], bgf[4], buf[4];
#pragma unroll
        for (int i = 0; i < 4; ++i)
            af[i] = *(const bf16x8*)&As[wm + i * 16 + l16][quad * 8];
#pragma unroll
        for (int j = 0; j < 4; ++j) {
            bgf[j] = *(const bf16x8*)&Bg[wn + j * 16 + l16][quad * 8];
            buf[j] = *(const bf16x8*)&Bu[wn + j * 16 + l16][quad * 8];
        }
#pragma unroll
        for (int i = 0; i < 4; ++i)
#pragma unroll
            for (int j = 0; j < 4; ++j) {
                accg[i][j] = __builtin_amdgcn_mfma_f32_16x16x32_bf16(
                    af[i], bgf[j], accg[i][j], 0, 0, 0);
                accu[i][j] = __builtin_amdgcn_mfma_f32_16x16x32_bf16(
                    af[i], buf[j], accu[i][j], 0, 0, 0);
            }
        __syncthreads();
    }

    // epilogue: silu(g)*u -> bf16 act
#pragma unroll
    for (int j = 0; j < 4; ++j) {
        const int nl = n0 + wn + j * 16 + l16;
        const float gbv = gbp[nl];
        const float ubv = ubp[nl];
#pragma unroll
        for (int i = 0; i < 4; ++i) {
#pragma unroll
            for (int ii = 0; ii < 4; ++ii) {
                const int ml = wm + i * 16 + quad * 4 + ii;
                const int orow = or_lds[ml];
                if (orow >= 0) {
                    const float g = accg[i][j][ii] + gbv;
                    const float u = accu[i][j][ii] + ubv;
                    const float a = g * u / (1.0f + __expf(-g));
                    act[(size_t)orow * IDIM + nl] = f2bf(a);
                }
            }
        }
    }
}

// ------------------------------------------------------- down-proj GEMM ----
// A = act rows (bf16) gathered by row_list, K = IDIM.
// B = down_w [K, HDIM] fp32 -> bf16 transposed.
// Epilogue: atomicAdd(out[token][n], w * (acc + down_bias)), fp32.
__global__ __launch_bounds__(256) void down_kernel(
    const unsigned short* __restrict__ act,    // [2T, IDIM] bf16
    const float* __restrict__ dw,
    const float* __restrict__ db,
    const int* __restrict__ counts,
    const int* __restrict__ tok_list,
    const float* __restrict__ wgt_list,
    const int* __restrict__ row_list,
    float* __restrict__ out)                   // [T, HDIM] fp32 (pre-zeroed)
{
    const int e  = blockIdx.x >> 4;
    const int mt = blockIdx.x & 15;
    const int n_e = counts[e];
    const int m0 = mt * BM;
    if (m0 >= n_e) return;
    const int n0 = blockIdx.y * BN;

    const float* dwp = dw + (size_t)e * IDIM * HDIM;
    const float* dbp = db + (size_t)e * HDIM;

    __shared__ unsigned short As[BM][KPAD];
    __shared__ unsigned short Bs[BN][KPAD];
    __shared__ int   gr_lds[BM];
    __shared__ int   or_lds[BM];
    __shared__ float w_lds[BM];

    const int tid = threadIdx.x;
    const int base = e * T_TOK;
    if (tid < BM) {
        const int m = m0 + tid;
        int g = -1, o = -1; float w = 0.0f;
        if (m < n_e) {
            g = row_list[base + m];    // A row = pair id
            o = tok_list[base + m];    // out row = token
            w = wgt_list[base + m];
        }
        gr_lds[tid] = g; or_lds[tid] = o; w_lds[tid] = w;
    }
    __syncthreads();

    const int ar = tid >> 1;
    const int ac = (tid & 1) * 16;
    const int arow = gr_lds[ar];
    const unsigned short* ap = (arow >= 0) ? (act + (size_t)arow * IDIM) : act;
    const int bn = (tid & 31) * 4;
    const int bk = (tid >> 5) * 4;

    const int wv = tid >> 6, lane = tid & 63;
    const int wm = (wv & 1) * 64, wn = (wv >> 1) * 64;
    const int l16 = lane & 15, quad = lane >> 4;

    f32x4 acc[4][4];
    const f32x4 zero = {0.0f, 0.0f, 0.0f, 0.0f};
#pragma unroll
    for (int i = 0; i < 4; ++i)
#pragma unroll
        for (int j = 0; j < 4; ++j) acc[i][j] = zero;

    for (int k0 = 0; k0 < IDIM; k0 += BK) {
        // A tile: already bf16
        uint4 v0 = {0u,0u,0u,0u}, v1 = {0u,0u,0u,0u};
        if (arow >= 0) {
            const uint4* p = (const uint4*)(ap + k0 + ac);
            v0 = p[0]; v1 = p[1];
        }
        *(uint4*)&As[ar][ac]     = v0;
        *(uint4*)&As[ar][ac + 8] = v1;
        // B tile: fp32 -> bf16 transpose
        {
            const size_t boff = (size_t)(k0 + bk) * HDIM + n0 + bn;
            const float4 r0 = *(const float4*)(dwp + boff);
            const float4 r1 = *(const float4*)(dwp + boff + HDIM);
            const float4 r2 = *(const float4*)(dwp + boff + 2 * HDIM);
            const float4 r3 = *(const float4*)(dwp + boff + 3 * HDIM);
            ushort4 w;
            w.x = f2bf(r0.x); w.y = f2bf(r1.x); w.z = f2bf(r2.x); w.w = f2bf(r3.x);
            *(ushort4*)&Bs[bn + 0][bk] = w;
            w.x = f2bf(r0.y); w.y = f2bf(r1.y); w.z = f2bf(r2.y); w.w = f2bf(r3.y);
            *(ushort4*)&Bs[bn + 1][bk] = w;
            w.x = f2bf(r0.z); w.y = f2bf(r1.z); w.z = f2bf(r2.z); w.w = f2bf(r3.z);
            *(ushort4*)&Bs[bn + 2][bk] = w;
            w.x = f2bf(r0.w); w.y = f2bf(r1.w); w.z = f2bf(r2.w); w.w = f2bf(r3.w);
            *(ushort4*)&Bs[bn + 3][bk] = w;
        }
        __syncthreads();

        bf16x8 af[4], bfr[4];
#pragma unroll
        for (int i = 0; i < 4; ++i)
            af[i] = *(const bf16x8*)&As[wm + i * 16 + l16][quad * 8];
#pragma unroll
        for (int j = 0; j < 4; ++j)
            bfr[j] = *(const bf16x8*)&Bs[wn + j * 16 + l16][quad * 8];
#pragma unroll
        for (int i = 0; i < 4; ++i)
#pragma unroll
            for (int j = 0; j < 4; ++j)
                acc[i][j] = __builtin_amdgcn_mfma_f32_16x16x32_bf16(
                    af[i], bfr[j], acc[i][j], 0, 0, 0);
        __syncthreads();
    }

#pragma unroll
    for (int j = 0; j < 4; ++j) {
        const int nl = n0 + wn + j * 16 + l16;
        const float bv = dbp[nl];
#pragma unroll
        for (int i = 0; i < 4; ++i) {
#pragma unroll
            for (int ii = 0; ii < 4; ++ii) {
                const int ml = wm + i * 16 + quad * 4 + ii;
                const int tt = or_lds[ml];
                if (tt >= 0)
                    atomicAdd(&out[(size_t)tt * HDIM + nl],
                              w_lds[ml] * (acc[i][j][ii] + bv));
            }
        }
    }
}

// ---------------------------------------------------------------- launch ----
extern "C" void kernel_launch(void* const* d_in, const int* in_sizes, int n_in,
                              void* d_out, int out_size, void* d_ws, size_t ws_size,
                              hipStream_t stream)
{
    const float* x      = (const float*)d_in[0];
    const float* rw     = (const float*)d_in[1];
    const float* gate_w = (const float*)d_in[2];
    const float* up_w   = (const float*)d_in[3];
    const float* down_w = (const float*)d_in[4];
    const float* gate_b = (const float*)d_in[5];
    const float* up_b   = (const float*)d_in[6];
    const float* down_b = (const float*)d_in[7];
    float* out = (float*)d_out;

    // workspace (~11.7 MB)
    char* ws = (char*)d_ws;
    int*   counts   = (int*)ws;                                 // 256 B slot
    int*   tok_list = (int*)(ws + 256);
    float* wgt_list = (float*)(ws + 256 + 65536);
    int*   row_list = (int*)(ws + 256 + 2 * 65536);
    unsigned short* act = (unsigned short*)(ws + 256 + 3 * 65536 + 768); // 256-align

    // d_out and counts are poisoned 0xAA before every timed launch
    (void)hipMemsetAsync(counts, 0, 256, stream);
    (void)hipMemsetAsync(out, 0, (size_t)out_size * sizeof(float), stream);

    router_kernel<<<T_TOK / 4, 256, 0, stream>>>(x, rw, counts, tok_list,
                                                 wgt_list, row_list);

    dim3 g1(NEXP * MT_SLOTS, IDIM / BN, 1);
    gateup_kernel<<<g1, 256, 0, stream>>>(
        x, gate_w, up_w, gate_b, up_b, counts, tok_list, row_list, act);

    dim3 g2(NEXP * MT_SLOTS, HDIM / BN, 1);
    down_kernel<<<g2, 256, 0, stream>>>(
        act, down_w, down_b, counts, tok_list, wgt_list, row_list, out);
}

// Round 5
// 364.864 us; speedup vs baseline: 1.6537x; 1.6537x over previous
//
#include <hip/hip_runtime.h>

// DeepseekV3MoEToA2AAdapter: T=2048 tokens, H=1024, E=8, I=1408, top-2.
// fp32 I/O, bf16 MFMA internally.
#define T_TOK 2048
#define HDIM  1024
#define NEXP  8
#define IDIM  1408

#define BM 128
#define BN 64
#define BK 32
#define KPAD 40     // bf16 elems; 80 B rows, 16B-aligned
#define MT_SLOTS 16
#define GU_NT 22    // IDIM / BN
#define DN_NT 16    // HDIM / BN

typedef __attribute__((ext_vector_type(8))) short bf16x8;
typedef __attribute__((ext_vector_type(4))) float f32x4;

static __device__ __forceinline__ unsigned short f2bf(float f) {
    union { float f; unsigned u; } a; a.f = f;
    return (unsigned short)((a.u + 0x7fffu + ((a.u >> 16) & 1u)) >> 16);
}

// ---------------------------------------------------------------- router ----
__global__ __launch_bounds__(256) void router_kernel(
    const float* __restrict__ x,        // [T, H]
    const float* __restrict__ rw,       // [H, E]
    int*   __restrict__ counts,         // [E]
    int*   __restrict__ tok_list,       // [E][T]
    float* __restrict__ wgt_list,       // [E][T]
    int*   __restrict__ row_list)       // [E][T]  pair row id (2t / 2t+1)
{
    const int wave = (blockIdx.x * blockDim.x + threadIdx.x) >> 6;
    const int lane = threadIdx.x & 63;
    if (wave >= T_TOK) return;
    const int t = wave;

    float xr[16];
    const float* xp = x + (size_t)t * HDIM;
#pragma unroll
    for (int i = 0; i < 16; ++i) xr[i] = xp[lane + 64 * i];

    double logits[NEXP];
#pragma unroll
    for (int e = 0; e < NEXP; ++e) {
        double s = 0.0;
#pragma unroll
        for (int i = 0; i < 16; ++i) {
            const int j = lane + 64 * i;
            s += (double)xr[i] * (double)rw[j * NEXP + e];
        }
#pragma unroll
        for (int off = 32; off > 0; off >>= 1)
            s += __shfl_down(s, off, 64);
        logits[e] = s;
    }

    if (lane == 0) {
        int e1 = 0;
        for (int e = 1; e < NEXP; ++e) if (logits[e] > logits[e1]) e1 = e;
        int e2 = -1;
        for (int e = 0; e < NEXP; ++e) {
            if (e == e1) continue;
            if (e2 < 0 || logits[e] > logits[e2]) e2 = e;
        }
        const double w1 = 1.0 / (1.0 + exp(logits[e2] - logits[e1]));
        const double w2 = 1.0 - w1;
        int p1 = atomicAdd(&counts[e1], 1);
        tok_list[e1 * T_TOK + p1] = t;
        wgt_list[e1 * T_TOK + p1] = (float)w1;
        row_list[e1 * T_TOK + p1] = 2 * t;
        int p2 = atomicAdd(&counts[e2], 1);
        tok_list[e2 * T_TOK + p2] = t;
        wgt_list[e2 * T_TOK + p2] = (float)w2;
        row_list[e2 * T_TOK + p2] = 2 * t + 1;
    }
}

// -------------------------------------------------- fused gate+up GEMM -----
// 128x64 tile, reg-double-buffered staging. Grid flat-swizzled so all m-tiles
// of one (e,nt) share flat%8 (same XCD) -> weight panel L2 reuse.
__global__ __launch_bounds__(256) void gateup_kernel(
    const float* __restrict__ x,
    const float* __restrict__ gw, const float* __restrict__ uw,
    const float* __restrict__ gb, const float* __restrict__ ub,
    const int* __restrict__ counts,
    const int* __restrict__ tok_list,
    const int* __restrict__ row_list,
    unsigned short* __restrict__ act)          // [2T, IDIM] bf16
{
    const int flat = blockIdx.x;
    const int xcd  = flat & 7;
    const int q    = flat >> 3;
    const int mt   = q & 15;
    const int slot = q >> 4;
    const int P    = slot * 8 + xcd;   // 0..175 = (e, nt)
    const int e    = P / GU_NT;
    const int nt   = P % GU_NT;
    const int n_e  = counts[e];
    const int m0   = mt * BM;
    if (m0 >= n_e) return;
    const int n0 = nt * BN;

    const float* gwp = gw + (size_t)e * HDIM * IDIM;
    const float* uwp = uw + (size_t)e * HDIM * IDIM;
    const float* gbp = gb + (size_t)e * IDIM;
    const float* ubp = ub + (size_t)e * IDIM;

    __shared__ unsigned short As[BM][KPAD];
    __shared__ unsigned short Bg[BN][KPAD];
    __shared__ unsigned short Bu[BN][KPAD];
    __shared__ int gr_lds[BM];
    __shared__ int or_lds[BM];

    const int tid = threadIdx.x;
    const int base = e * T_TOK;
    if (tid < BM) {
        const int m = m0 + tid;
        int g = -1, o = -1;
        if (m < n_e) { g = tok_list[base + m]; o = row_list[base + m]; }
        gr_lds[tid] = g; or_lds[tid] = o;
    }
    __syncthreads();

    // A staging: 2 threads/row, 16 fp32 each
    const int ar = tid >> 1;
    const int ac = (tid & 1) * 16;
    const int arow = gr_lds[ar];
    const float* ap = x + (size_t)(arow < 0 ? 0 : arow) * HDIM;
    // B staging: tid<128 -> gate, tid>=128 -> up; 4n x 4k per thread
    const int bn = (tid & 15) * 4;
    const int bk = ((tid >> 4) & 7) * 4;
    const float* bp_base = ((tid >> 7) ? uwp : gwp);
    unsigned short* Bdst = ((tid >> 7) ? &Bu[0][0] : &Bg[0][0]);

    const int wv = tid >> 6, lane = tid & 63;
    const int wm = (wv & 1) * 64, wn = (wv >> 1) * 32;
    const int l16 = lane & 15, quad = lane >> 4;

    f32x4 accg[4][2], accu[4][2];
    const f32x4 zero = {0.0f, 0.0f, 0.0f, 0.0f};
#pragma unroll
    for (int i = 0; i < 4; ++i)
#pragma unroll
        for (int j = 0; j < 2; ++j) { accg[i][j] = zero; accu[i][j] = zero; }

    const float4 z4 = {0.f, 0.f, 0.f, 0.f};
    float4 A0 = z4, A1 = z4, A2 = z4, A3 = z4, B0, B1, B2, B3;
    // prologue prefetch (k0 = 0)
    if (arow >= 0) {
        A0 = *(const float4*)(ap + ac);
        A1 = *(const float4*)(ap + ac + 4);
        A2 = *(const float4*)(ap + ac + 8);
        A3 = *(const float4*)(ap + ac + 12);
    }
    {
        const float* bp = bp_base + (size_t)bk * IDIM + n0 + bn;
        B0 = *(const float4*)(bp);
        B1 = *(const float4*)(bp + IDIM);
        B2 = *(const float4*)(bp + 2 * IDIM);
        B3 = *(const float4*)(bp + 3 * IDIM);
    }

    for (int k0 = 0; k0 < HDIM; k0 += BK) {
        __syncthreads();   // LDS from previous iter fully consumed
        {
            ushort4 o;
            const float* a0 = (const float*)&A0; const float* a1 = (const float*)&A1;
            const float* a2 = (const float*)&A2; const float* a3 = (const float*)&A3;
            o.x = f2bf(a0[0]); o.y = f2bf(a0[1]); o.z = f2bf(a0[2]); o.w = f2bf(a0[3]);
            *(ushort4*)&As[ar][ac] = o;
            o.x = f2bf(a1[0]); o.y = f2bf(a1[1]); o.z = f2bf(a1[2]); o.w = f2bf(a1[3]);
            *(ushort4*)&As[ar][ac + 4] = o;
            o.x = f2bf(a2[0]); o.y = f2bf(a2[1]); o.z = f2bf(a2[2]); o.w = f2bf(a2[3]);
            *(ushort4*)&As[ar][ac + 8] = o;
            o.x = f2bf(a3[0]); o.y = f2bf(a3[1]); o.z = f2bf(a3[2]); o.w = f2bf(a3[3]);
            *(ushort4*)&As[ar][ac + 12] = o;
            const float* b0 = (const float*)&B0; const float* b1 = (const float*)&B1;
            const float* b2 = (const float*)&B2; const float* b3 = (const float*)&B3;
#pragma unroll
            for (int jj = 0; jj < 4; ++jj) {
                ushort4 w;
                w.x = f2bf(b0[jj]); w.y = f2bf(b1[jj]);
                w.z = f2bf(b2[jj]); w.w = f2bf(b3[jj]);
                *(ushort4*)&Bdst[(bn + jj) * KPAD + bk] = w;
            }
        }
        __syncthreads();

        // prefetch next K tile (overlaps the MFMA section below)
        const int kn = k0 + BK;
        if (kn < HDIM) {
            if (arow >= 0) {
                A0 = *(const float4*)(ap + kn + ac);
                A1 = *(const float4*)(ap + kn + ac + 4);
                A2 = *(const float4*)(ap + kn + ac + 8);
                A3 = *(const float4*)(ap + kn + ac + 12);
            }
            const float* bp = bp_base + (size_t)(kn + bk) * IDIM + n0 + bn;
            B0 = *(const float4*)(bp);
            B1 = *(const float4*)(bp + IDIM);
            B2 = *(const float4*)(bp + 2 * IDIM);
            B3 = *(const float4*)(bp + 3 * IDIM);
        }

        bf16x8 af[4], bgf[2], buf[2];
#pragma unroll
        for (int i = 0; i < 4; ++i)
            af[i] = *(const bf16x8*)&As[wm + i * 16 + l16][quad * 8];
#pragma unroll
        for (int j = 0; j < 2; ++j) {
            bgf[j] = *(const bf16x8*)&Bg[wn + j * 16 + l16][quad * 8];
            buf[j] = *(const bf16x8*)&Bu[wn + j * 16 + l16][quad * 8];
        }
#pragma unroll
        for (int i = 0; i < 4; ++i)
#pragma unroll
            for (int j = 0; j < 2; ++j) {
                accg[i][j] = __builtin_amdgcn_mfma_f32_16x16x32_bf16(
                    af[i], bgf[j], accg[i][j], 0, 0, 0);
                accu[i][j] = __builtin_amdgcn_mfma_f32_16x16x32_bf16(
                    af[i], buf[j], accu[i][j], 0, 0, 0);
            }
    }

    // epilogue: silu(g)*u -> bf16 act
#pragma unroll
    for (int j = 0; j < 2; ++j) {
        const int nl = n0 + wn + j * 16 + l16;
        const float gbv = gbp[nl];
        const float ubv = ubp[nl];
#pragma unroll
        for (int i = 0; i < 4; ++i) {
#pragma unroll
            for (int ii = 0; ii < 4; ++ii) {
                const int ml = wm + i * 16 + quad * 4 + ii;
                const int orow = or_lds[ml];
                if (orow >= 0) {
                    const float g = accg[i][j][ii] + gbv;
                    const float u = accu[i][j][ii] + ubv;
                    act[(size_t)orow * IDIM + nl] =
                        f2bf(g * u / (1.0f + __expf(-g)));
                }
            }
        }
    }
}

// ------------------------------------------------------- down-proj GEMM ----
// A = act rows (bf16), K = IDIM; B = down_w fp32 -> bf16.
// Non-atomic: y2[pair_row] = w * (acc + down_bias); combine pass sums pairs.
__global__ __launch_bounds__(256) void down_kernel(
    const unsigned short* __restrict__ act,    // [2T, IDIM] bf16
    const float* __restrict__ dw,
    const float* __restrict__ db,
    const int* __restrict__ counts,
    const float* __restrict__ wgt_list,
    const int* __restrict__ row_list,
    float* __restrict__ y2)                    // [2T, HDIM] fp32
{
    const int flat = blockIdx.x;
    const int xcd  = flat & 7;
    const int q    = flat >> 3;
    const int mt   = q & 15;
    const int slot = q >> 4;
    const int P    = slot * 8 + xcd;   // 0..127 = (e, nt)
    const int e    = P / DN_NT;
    const int nt   = P % DN_NT;
    const int n_e  = counts[e];
    const int m0   = mt * BM;
    if (m0 >= n_e) return;
    const int n0 = nt * BN;

    const float* dwp = dw + (size_t)e * IDIM * HDIM;
    const float* dbp = db + (size_t)e * HDIM;

    __shared__ unsigned short As[BM][KPAD];
    __shared__ unsigned short Bs[BN][KPAD];
    __shared__ int   r_lds[BM];
    __shared__ float w_lds[BM];

    const int tid = threadIdx.x;
    const int base = e * T_TOK;
    if (tid < BM) {
        const int m = m0 + tid;
        int r = -1; float w = 0.0f;
        if (m < n_e) { r = row_list[base + m]; w = wgt_list[base + m]; }
        r_lds[tid] = r; w_lds[tid] = w;
    }
    __syncthreads();

    const int ar = tid >> 1;
    const int ac = (tid & 1) * 16;
    const int arow = r_lds[ar];
    const unsigned short* ap = act + (size_t)(arow < 0 ? 0 : arow) * IDIM;
    const int bn = (tid & 15) * 4;
    const int bk = ((tid >> 4) & 7) * 4;
    const bool bact = (tid < 128);

    const int wv = tid >> 6, lane = tid & 63;
    const int wm = (wv & 1) * 64, wn = (wv >> 1) * 32;
    const int l16 = lane & 15, quad = lane >> 4;

    f32x4 acc[4][2];
    const f32x4 zero = {0.0f, 0.0f, 0.0f, 0.0f};
#pragma unroll
    for (int i = 0; i < 4; ++i)
#pragma unroll
        for (int j = 0; j < 2; ++j) acc[i][j] = zero;

    uint4 PA0 = {0u,0u,0u,0u}, PA1 = {0u,0u,0u,0u};
    float4 B0, B1, B2, B3;
    if (arow >= 0) {
        PA0 = *(const uint4*)(ap + ac);
        PA1 = *(const uint4*)(ap + ac + 8);
    }
    if (bact) {
        const float* bp = dwp + (size_t)bk * HDIM + n0 + bn;
        B0 = *(const float4*)(bp);
        B1 = *(const float4*)(bp + HDIM);
        B2 = *(const float4*)(bp + 2 * HDIM);
        B3 = *(const float4*)(bp + 3 * HDIM);
    }

    for (int k0 = 0; k0 < IDIM; k0 += BK) {
        __syncthreads();
        *(uint4*)&As[ar][ac]     = PA0;
        *(uint4*)&As[ar][ac + 8] = PA1;
        if (bact) {
            const float* b0 = (const float*)&B0; const float* b1 = (const float*)&B1;
            const float* b2 = (const float*)&B2; const float* b3 = (const float*)&B3;
#pragma unroll
            for (int jj = 0; jj < 4; ++jj) {
                ushort4 w;
                w.x = f2bf(b0[jj]); w.y = f2bf(b1[jj]);
                w.z = f2bf(b2[jj]); w.w = f2bf(b3[jj]);
                *(ushort4*)&Bs[bn + jj][bk] = w;
            }
        }
        __syncthreads();

        const int kn = k0 + BK;
        if (kn < IDIM) {
            if (arow >= 0) {
                PA0 = *(const uint4*)(ap + kn + ac);
                PA1 = *(const uint4*)(ap + kn + ac + 8);
            }
            if (bact) {
                const float* bp = dwp + (size_t)(kn + bk) * HDIM + n0 + bn;
                B0 = *(const float4*)(bp);
                B1 = *(const float4*)(bp + HDIM);
                B2 = *(const float4*)(bp + 2 * HDIM);
                B3 = *(const float4*)(bp + 3 * HDIM);
            }
        }

        bf16x8 af[4], bfr[2];
#pragma unroll
        for (int i = 0; i < 4; ++i)
            af[i] = *(const bf16x8*)&As[wm + i * 16 + l16][quad * 8];
#pragma unroll
        for (int j = 0; j < 2; ++j)
            bfr[j] = *(const bf16x8*)&Bs[wn + j * 16 + l16][quad * 8];
#pragma unroll
        for (int i = 0; i < 4; ++i)
#pragma unroll
            for (int j = 0; j < 2; ++j)
                acc[i][j] = __builtin_amdgcn_mfma_f32_16x16x32_bf16(
                    af[i], bfr[j], acc[i][j], 0, 0, 0);
    }

#pragma unroll
    for (int j = 0; j < 2; ++j) {
        const int nl = n0 + wn + j * 16 + l16;
        const float bv = dbp[nl];
#pragma unroll
        for (int i = 0; i < 4; ++i) {
#pragma unroll
            for (int ii = 0; ii < 4; ++ii) {
                const int ml = wm + i * 16 + quad * 4 + ii;
                const int rr = r_lds[ml];
                if (rr >= 0)
                    y2[(size_t)rr * HDIM + nl] = w_lds[ml] * (acc[i][j][ii] + bv);
            }
        }
    }
}

// --------------------------------------------------------------- combine ----
__global__ __launch_bounds__(256) void combine_kernel(
    const float* __restrict__ y2, float* __restrict__ out)
{
    const int idx = (blockIdx.x * 256 + threadIdx.x) * 4;   // < T*H
    const int t = idx >> 10;           // HDIM == 1024
    const int h = idx & 1023;
    const float4 a = *(const float4*)(y2 + ((size_t)2 * t) * HDIM + h);
    const float4 b = *(const float4*)(y2 + ((size_t)2 * t + 1) * HDIM + h);
    float4 o;
    o.x = a.x + b.x; o.y = a.y + b.y; o.z = a.z + b.z; o.w = a.w + b.w;
    *(float4*)(out + idx) = o;
}

// ---------------------------------------------------------------- launch ----
extern "C" void kernel_launch(void* const* d_in, const int* in_sizes, int n_in,
                              void* d_out, int out_size, void* d_ws, size_t ws_size,
                              hipStream_t stream)
{
    const float* x      = (const float*)d_in[0];
    const float* rw     = (const float*)d_in[1];
    const float* gate_w = (const float*)d_in[2];
    const float* up_w   = (const float*)d_in[3];
    const float* down_w = (const float*)d_in[4];
    const float* gate_b = (const float*)d_in[5];
    const float* up_b   = (const float*)d_in[6];
    const float* down_b = (const float*)d_in[7];
    float* out = (float*)d_out;

    // workspace (~28.5 MB)
    char* ws = (char*)d_ws;
    int*   counts   = (int*)ws;
    int*   tok_list = (int*)(ws + 256);
    float* wgt_list = (float*)(ws + 256 + 65536);
    int*   row_list = (int*)(ws + 256 + 2 * 65536);
    unsigned short* act = (unsigned short*)(ws + 256 + 3 * 65536);          // 11.53 MB
    float* y2 = (float*)(ws + 256 + 3 * 65536 + (size_t)2 * T_TOK * IDIM * 2); // 16 MB

    (void)hipMemsetAsync(counts, 0, 256, stream);

    router_kernel<<<T_TOK / 4, 256, 0, stream>>>(x, rw, counts, tok_list,
                                                 wgt_list, row_list);

    gateup_kernel<<<8 * GU_NT * MT_SLOTS, 256, 0, stream>>>(
        x, gate_w, up_w, gate_b, up_b, counts, tok_list, row_list, act);

    down_kernel<<<8 * DN_NT * MT_SLOTS, 256, 0, stream>>>(
        act, down_w, down_b, counts, wgt_list, row_list, y2);

    combine_kernel<<<(T_TOK * HDIM / 4) / 256, 256, 0, stream>>>(y2, out);
}

// Round 7
// 356.056 us; speedup vs baseline: 1.6946x; 1.0247x over previous
//
#include <hip/hip_runtime.h>

// DeepseekV3MoEToA2AAdapter: T=2048 tokens, H=1024, E=8, I=1408, top-2.
// fp32 I/O; weights pre-converted to bf16 [E][N][K] once, bf16 MFMA GEMMs.
#define T_TOK 2048
#define HDIM  1024
#define NEXP  8
#define IDIM  1408

#define BM 128
#define BN 64
#define BK 32
#define KPAD 40     // bf16 elems; 80 B rows, 16B-aligned, conflict-free frag reads
#define MT_SLOTS 16
#define GU_NT 22    // IDIM / BN
#define DN_NT 16    // HDIM / BN
#define DK_HALF 704 // IDIM / 2 (split-K for down)

typedef __attribute__((ext_vector_type(8))) short bf16x8;
typedef __attribute__((ext_vector_type(4))) float f32x4;

static __device__ __forceinline__ unsigned short f2bf(float f) {
    union { float f; unsigned u; } a; a.f = f;
    return (unsigned short)((a.u + 0x7fffu + ((a.u >> 16) & 1u)) >> 16);
}

// ---------------------------------------------------------------- router ----
__global__ __launch_bounds__(256) void router_kernel(
    const float* __restrict__ x,        // [T, H]
    const float* __restrict__ rw,       // [H, E]
    int*   __restrict__ counts,         // [E]
    int*   __restrict__ tok_list,       // [E][T]
    float* __restrict__ wgt_list,       // [E][T]
    int*   __restrict__ row_list)       // [E][T]  pair row id (2t / 2t+1)
{
    const int wave = (blockIdx.x * blockDim.x + threadIdx.x) >> 6;
    const int lane = threadIdx.x & 63;
    if (wave >= T_TOK) return;
    const int t = wave;

    float xr[16];
    const float* xp = x + (size_t)t * HDIM;
#pragma unroll
    for (int i = 0; i < 16; ++i) xr[i] = xp[lane + 64 * i];

    double logits[NEXP];
#pragma unroll
    for (int e = 0; e < NEXP; ++e) {
        double s = 0.0;
#pragma unroll
        for (int i = 0; i < 16; ++i) {
            const int j = lane + 64 * i;
            s += (double)xr[i] * (double)rw[j * NEXP + e];
        }
#pragma unroll
        for (int off = 32; off > 0; off >>= 1)
            s += __shfl_down(s, off, 64);
        logits[e] = s;
    }

    if (lane == 0) {
        int e1 = 0;
        for (int e = 1; e < NEXP; ++e) if (logits[e] > logits[e1]) e1 = e;
        int e2 = -1;
        for (int e = 0; e < NEXP; ++e) {
            if (e == e1) continue;
            if (e2 < 0 || logits[e] > logits[e2]) e2 = e;
        }
        const double w1 = 1.0 / (1.0 + exp(logits[e2] - logits[e1]));
        const double w2 = 1.0 - w1;
        int p1 = atomicAdd(&counts[e1], 1);
        tok_list[e1 * T_TOK + p1] = t;
        wgt_list[e1 * T_TOK + p1] = (float)w1;
        row_list[e1 * T_TOK + p1] = 2 * t;
        int p2 = atomicAdd(&counts[e2], 1);
        tok_list[e2 * T_TOK + p2] = t;
        wgt_list[e2 * T_TOK + p2] = (float)w2;
        row_list[e2 * T_TOK + p2] = 2 * t + 1;
    }
}

// ----------------------------------------------- weight convert+transpose ---
// src fp32 [E][K][N]  ->  dst bf16 [E][N][K].  64x64 tiles via LDS.
__global__ __launch_bounds__(256) void wtrans_kernel(
    const float* __restrict__ src, unsigned short* __restrict__ dst,
    int K, int N)
{
    const int e  = blockIdx.z;
    const int k0 = blockIdx.x * 64;
    const int n0 = blockIdx.y * 64;
    src += (size_t)e * K * N;
    dst += (size_t)e * N * K;
    __shared__ unsigned short tile[64][72];   // [n][k], row = 144 B (16B-aligned)
    const int t = threadIdx.x;
    const int c  = (t & 15) * 4;   // n within tile
    const int r0 = t >> 4;         // k within tile (16 rows/pass)
#pragma unroll
    for (int p = 0; p < 4; ++p) {
        const int r = r0 + p * 16;
        const float4 v = *(const float4*)(src + (size_t)(k0 + r) * N + n0 + c);
        tile[c + 0][r] = f2bf(v.x);
        tile[c + 1][r] = f2bf(v.y);
        tile[c + 2][r] = f2bf(v.z);
        tile[c + 3][r] = f2bf(v.w);
    }
    __syncthreads();
    const int n   = t >> 2;
    const int ch0 = (t & 3) * 2;   // two 8-elem (16 B) chunks
#pragma unroll
    for (int q = 0; q < 2; ++q) {
        const int ch = ch0 + q;
        const uint4 v = *(const uint4*)&tile[n][ch * 8];
        *(uint4*)(dst + (size_t)(n0 + n) * K + k0 + ch * 8) = v;
    }
}

// ------------------------------------------------------------- x -> bf16 ---
__global__ __launch_bounds__(256) void xconv_kernel(
    const float* __restrict__ src, unsigned short* __restrict__ dst)
{
    const int i = (blockIdx.x * 256 + threadIdx.x) * 8;
    const float4 v0 = *(const float4*)(src + i);
    const float4 v1 = *(const float4*)(src + i + 4);
    ushort4 o0, o1;
    o0.x = f2bf(v0.x); o0.y = f2bf(v0.y); o0.z = f2bf(v0.z); o0.w = f2bf(v0.w);
    o1.x = f2bf(v1.x); o1.y = f2bf(v1.y); o1.z = f2bf(v1.z); o1.w = f2bf(v1.w);
    *(ushort4*)(dst + i)     = o0;
    *(ushort4*)(dst + i + 4) = o1;
}

// -------------------------------------------------- fused gate+up GEMM -----
// A = x_bf rows gathered by tok_list; B = gwt/uwt bf16 [E][I][H] (pre-transposed).
// Staging is pure uint4 copies (no conversion VALU). Reg-double-buffered.
__global__ __launch_bounds__(256) void gateup_kernel(
    const unsigned short* __restrict__ xb,    // [T,H] bf16
    const unsigned short* __restrict__ gwt,   // [E][I][H] bf16
    const unsigned short* __restrict__ uwt,   // [E][I][H] bf16
    const float* __restrict__ gb, const float* __restrict__ ub,
    const int* __restrict__ counts,
    const int* __restrict__ tok_list,
    const int* __restrict__ row_list,
    unsigned short* __restrict__ act)         // [2T, IDIM] bf16
{
    const int flat = blockIdx.x;
    const int xcd  = flat & 7;
    const int q    = flat >> 3;
    const int mt   = q & 15;
    const int slot = q >> 4;
    const int P    = slot * 8 + xcd;   // 0..175 = (e, nt), fixed XCD per (e,nt)
    const int e    = P / GU_NT;
    const int nt   = P % GU_NT;
    const int n_e  = counts[e];
    const int m0   = mt * BM;
    if (m0 >= n_e) return;
    const int n0 = nt * BN;

    const unsigned short* gwp = gwt + (size_t)e * IDIM * HDIM;
    const unsigned short* uwp = uwt + (size_t)e * IDIM * HDIM;
    const float* gbp = gb + (size_t)e * IDIM;
    const float* ubp = ub + (size_t)e * IDIM;

    __shared__ unsigned short As[BM][KPAD];
    __shared__ unsigned short Bg[BN][KPAD];
    __shared__ unsigned short Bu[BN][KPAD];
    __shared__ int gr_lds[BM];
    __shared__ int or_lds[BM];

    const int tid = threadIdx.x;
    const int base = e * T_TOK;
    if (tid < BM) {
        const int m = m0 + tid;
        int g = -1, o = -1;
        if (m < n_e) { g = tok_list[base + m]; o = row_list[base + m]; }
        gr_lds[tid] = g; or_lds[tid] = o;
    }
    __syncthreads();

    // A staging: 2 threads/row, 16 bf16 (32 B) each
    const int ar = tid >> 1;
    const int ac = (tid & 1) * 16;
    const int arow = gr_lds[ar];
    const unsigned short* ap = xb + (size_t)(arow < 0 ? 0 : arow) * HDIM;
    // B staging: tid<128 -> gate, else up; 2 threads/row, 16 bf16 each
    const int u   = tid & 127;
    const int brow = u >> 1;
    const int bch  = (u & 1) * 16;
    const unsigned short* bsrc =
        ((tid >> 7) ? uwp : gwp) + (size_t)(n0 + brow) * HDIM + bch;
    unsigned short* Bdst =
        ((tid >> 7) ? &Bu[0][0] : &Bg[0][0]) + brow * KPAD + bch;

    const int wv = tid >> 6, lane = tid & 63;
    const int wm = (wv & 1) * 64, wn = (wv >> 1) * 32;
    const int l16 = lane & 15, quad = lane >> 4;

    f32x4 accg[4][2], accu[4][2];
    const f32x4 zero = {0.0f, 0.0f, 0.0f, 0.0f};
#pragma unroll
    for (int i = 0; i < 4; ++i)
#pragma unroll
        for (int j = 0; j < 2; ++j) { accg[i][j] = zero; accu[i][j] = zero; }

    uint4 PA0 = {0,0,0,0}, PA1 = {0,0,0,0}, PB0, PB1;
    if (arow >= 0) {
        PA0 = *(const uint4*)(ap + ac);
        PA1 = *(const uint4*)(ap + ac + 8);
    }
    PB0 = *(const uint4*)(bsrc);
    PB1 = *(const uint4*)(bsrc + 8);

    for (int k0 = 0; k0 < HDIM; k0 += BK) {
        __syncthreads();
        *(uint4*)&As[ar][ac]       = PA0;
        *(uint4*)&As[ar][ac + 8]   = PA1;
        *(uint4*)(Bdst)            = PB0;
        *(uint4*)(Bdst + 8)        = PB1;
        __syncthreads();

        const int kn = k0 + BK;
        if (kn < HDIM) {
            if (arow >= 0) {
                PA0 = *(const uint4*)(ap + kn + ac);
                PA1 = *(const uint4*)(ap + kn + ac + 8);
            }
            PB0 = *(const uint4*)(bsrc + kn);
            PB1 = *(const uint4*)(bsrc + kn + 8);
        }

        bf16x8 af[4], bgf[2], buf[2];
#pragma unroll
        for (int i = 0; i < 4; ++i)
            af[i] = *(const bf16x8*)&As[wm + i * 16 + l16][quad * 8];
#pragma unroll
        for (int j = 0; j < 2; ++j) {
            bgf[j] = *(const bf16x8*)&Bg[wn + j * 16 + l16][quad * 8];
            buf[j] = *(const bf16x8*)&Bu[wn + j * 16 + l16][quad * 8];
        }
#pragma unroll
        for (int i = 0; i < 4; ++i)
#pragma unroll
            for (int j = 0; j < 2; ++j) {
                accg[i][j] = __builtin_amdgcn_mfma_f32_16x16x32_bf16(
                    af[i], bgf[j], accg[i][j], 0, 0, 0);
                accu[i][j] = __builtin_amdgcn_mfma_f32_16x16x32_bf16(
                    af[i], buf[j], accu[i][j], 0, 0, 0);
            }
    }

    // epilogue: silu(g)*u -> bf16 act
#pragma unroll
    for (int j = 0; j < 2; ++j) {
        const int nl = n0 + wn + j * 16 + l16;
        const float gbv = gbp[nl];
        const float ubv = ubp[nl];
#pragma unroll
        for (int i = 0; i < 4; ++i) {
#pragma unroll
            for (int ii = 0; ii < 4; ++ii) {
                const int ml = wm + i * 16 + quad * 4 + ii;
                const int orow = or_lds[ml];
                if (orow >= 0) {
                    const float g = accg[i][j][ii] + gbv;
                    const float uu = accu[i][j][ii] + ubv;
                    act[(size_t)orow * IDIM + nl] =
                        f2bf(g * uu / (1.0f + __expf(-g)));
                }
            }
        }
    }
}

// ------------------------------------------------------- down-proj GEMM ----
// Split-K=2. A = act rows (bf16); B = dwt bf16 [E][H][I] (pre-transposed).
// Epilogue: atomicAdd(y2[pair_row], w*(acc [+bias on slice 0])).
__global__ __launch_bounds__(256) void down_kernel(
    const unsigned short* __restrict__ act,   // [2T, IDIM] bf16
    const unsigned short* __restrict__ dwt,   // [E][H][I] bf16
    const float* __restrict__ db,
    const int* __restrict__ counts,
    const float* __restrict__ wgt_list,
    const int* __restrict__ row_list,
    float* __restrict__ y2)                   // [2T, HDIM] fp32 (zeroed)
{
    const int flat = blockIdx.x;
    const int xcd  = flat & 7;
    const int q    = flat >> 3;
    const int mt   = q & 15;
    const int slot = q >> 4;
    const int P    = slot * 8 + xcd;   // 0..255 = (sk, e, nt)
    const int sk   = P & 1;
    const int en   = P >> 1;
    const int e    = en >> 4;
    const int nt   = en & 15;
    const int n_e  = counts[e];
    const int m0   = mt * BM;
    if (m0 >= n_e) return;
    const int n0 = nt * BN;
    const int ks = sk * DK_HALF;

    const unsigned short* dwp = dwt + (size_t)e * HDIM * IDIM;
    const float* dbp = db + (size_t)e * HDIM;

    __shared__ unsigned short As[BM][KPAD];
    __shared__ unsigned short Bs[BN][KPAD];
    __shared__ int   r_lds[BM];
    __shared__ float w_lds[BM];

    const int tid = threadIdx.x;
    const int base = e * T_TOK;
    if (tid < BM) {
        const int m = m0 + tid;
        int r = -1; float w = 0.0f;
        if (m < n_e) { r = row_list[base + m]; w = wgt_list[base + m]; }
        r_lds[tid] = r; w_lds[tid] = w;
    }
    __syncthreads();

    const int ar = tid >> 1;
    const int ac = (tid & 1) * 16;
    const int arow = r_lds[ar];
    const unsigned short* ap = act + (size_t)(arow < 0 ? 0 : arow) * IDIM + ks;
    const int brow = tid >> 2;
    const int bch  = (tid & 3) * 8;
    const unsigned short* bsrc = dwp + (size_t)(n0 + brow) * IDIM + ks + bch;
    unsigned short* Bdst = &Bs[0][0] + brow * KPAD + bch;

    const int wv = tid >> 6, lane = tid & 63;
    const int wm = (wv & 1) * 64, wn = (wv >> 1) * 32;
    const int l16 = lane & 15, quad = lane >> 4;

    f32x4 acc[4][2];
    const f32x4 zero = {0.0f, 0.0f, 0.0f, 0.0f};
#pragma unroll
    for (int i = 0; i < 4; ++i)
#pragma unroll
        for (int j = 0; j < 2; ++j) acc[i][j] = zero;

    uint4 PA0 = {0,0,0,0}, PA1 = {0,0,0,0}, PB;
    if (arow >= 0) {
        PA0 = *(const uint4*)(ap + ac);        // FIX (r6 bug): was missing +ac
        PA1 = *(const uint4*)(ap + ac + 8);
    }
    PB = *(const uint4*)(bsrc);

    for (int k0 = 0; k0 < DK_HALF; k0 += BK) {
        __syncthreads();
        *(uint4*)&As[ar][ac]     = PA0;
        *(uint4*)&As[ar][ac + 8] = PA1;
        *(uint4*)(Bdst)          = PB;
        __syncthreads();

        const int kn = k0 + BK;
        if (kn < DK_HALF) {
            if (arow >= 0) {
                PA0 = *(const uint4*)(ap + kn + ac);
                PA1 = *(const uint4*)(ap + kn + ac + 8);
            }
            PB = *(const uint4*)(bsrc + kn);
        }

        bf16x8 af[4], bfr[2];
#pragma unroll
        for (int i = 0; i < 4; ++i)
            af[i] = *(const bf16x8*)&As[wm + i * 16 + l16][quad * 8];
#pragma unroll
        for (int j = 0; j < 2; ++j)
            bfr[j] = *(const bf16x8*)&Bs[wn + j * 16 + l16][quad * 8];
#pragma unroll
        for (int i = 0; i < 4; ++i)
#pragma unroll
            for (int j = 0; j < 2; ++j)
                acc[i][j] = __builtin_amdgcn_mfma_f32_16x16x32_bf16(
                    af[i], bfr[j], acc[i][j], 0, 0, 0);
    }

#pragma unroll
    for (int j = 0; j < 2; ++j) {
        const int nl = n0 + wn + j * 16 + l16;
        const float bv = (sk == 0) ? dbp[nl] : 0.0f;
#pragma unroll
        for (int i = 0; i < 4; ++i) {
#pragma unroll
            for (int ii = 0; ii < 4; ++ii) {
                const int ml = wm + i * 16 + quad * 4 + ii;
                const int rr = r_lds[ml];
                if (rr >= 0)
                    atomicAdd(&y2[(size_t)rr * HDIM + nl],
                              w_lds[ml] * (acc[i][j][ii] + bv));
            }
        }
    }
}

// --------------------------------------------------------------- combine ----
__global__ __launch_bounds__(256) void combine_kernel(
    const float* __restrict__ y2, float* __restrict__ out)
{
    const int idx = (blockIdx.x * 256 + threadIdx.x) * 4;   // < T*H
    const int t = idx >> 10;           // HDIM == 1024
    const int h = idx & 1023;
    const float4 a = *(const float4*)(y2 + ((size_t)2 * t) * HDIM + h);
    const float4 b = *(const float4*)(y2 + ((size_t)2 * t + 1) * HDIM + h);
    float4 o;
    o.x = a.x + b.x; o.y = a.y + b.y; o.z = a.z + b.z; o.w = a.w + b.w;
    *(float4*)(out + idx) = o;
}

// ---------------------------------------------------------------- launch ----
extern "C" void kernel_launch(void* const* d_in, const int* in_sizes, int n_in,
                              void* d_out, int out_size, void* d_ws, size_t ws_size,
                              hipStream_t stream)
{
    const float* x      = (const float*)d_in[0];
    const float* rw     = (const float*)d_in[1];
    const float* gate_w = (const float*)d_in[2];
    const float* up_w   = (const float*)d_in[3];
    const float* down_w = (const float*)d_in[4];
    const float* gate_b = (const float*)d_in[5];
    const float* up_b   = (const float*)d_in[6];
    const float* down_b = (const float*)d_in[7];
    float* out = (float*)d_out;

    // workspace layout (~85 MB; y2 aliases gwt, which is dead after gateup)
    char* ws = (char*)d_ws;
    size_t off = 0;
    int*   counts   = (int*)(ws + off);  off += 256;
    int*   tok_list = (int*)(ws + off);  off += 65536;
    float* wgt_list = (float*)(ws + off); off += 65536;
    int*   row_list = (int*)(ws + off);  off += 65536;
    unsigned short* x_bf = (unsigned short*)(ws + off); off += (size_t)T_TOK * HDIM * 2;       // 4 MB
    unsigned short* act  = (unsigned short*)(ws + off); off += (size_t)2 * T_TOK * IDIM * 2;   // 11.5 MB
    unsigned short* dwt  = (unsigned short*)(ws + off); off += (size_t)NEXP * IDIM * HDIM * 2; // 23 MB
    unsigned short* gwt  = (unsigned short*)(ws + off); off += (size_t)NEXP * IDIM * HDIM * 2; // 23 MB
    unsigned short* uwt  = (unsigned short*)(ws + off);                                        // 23 MB
    float* y2 = (float*)gwt;   // 16 MB, reused after gateup completes

    (void)hipMemsetAsync(counts, 0, 256, stream);

    // prep: weight transpose+convert, x convert (independent of router)
    wtrans_kernel<<<dim3(HDIM / 64, IDIM / 64, NEXP), 256, 0, stream>>>(
        gate_w, gwt, HDIM, IDIM);
    wtrans_kernel<<<dim3(HDIM / 64, IDIM / 64, NEXP), 256, 0, stream>>>(
        up_w, uwt, HDIM, IDIM);
    wtrans_kernel<<<dim3(IDIM / 64, HDIM / 64, NEXP), 256, 0, stream>>>(
        down_w, dwt, IDIM, HDIM);
    xconv_kernel<<<(T_TOK * HDIM / 8) / 256, 256, 0, stream>>>(x, x_bf);

    router_kernel<<<T_TOK / 4, 256, 0, stream>>>(x, rw, counts, tok_list,
                                                 wgt_list, row_list);

    gateup_kernel<<<8 * GU_NT * MT_SLOTS, 256, 0, stream>>>(
        x_bf, gwt, uwt, gate_b, up_b, counts, tok_list, row_list, act);

    // zero y2 (aliases gwt) after gateup, before down
    (void)hipMemsetAsync(y2, 0, (size_t)2 * T_TOK * HDIM * 4, stream);

    down_kernel<<<2 * 8 * DN_NT * MT_SLOTS, 256, 0, stream>>>(
        act, dwt, down_b, counts, wgt_list, row_list, y2);

    combine_kernel<<<(T_TOK * HDIM / 4) / 256, 256, 0, stream>>>(y2, out);
}

// Round 8
// 331.459 us; speedup vs baseline: 1.8204x; 1.0742x over previous
//
#include <hip/hip_runtime.h>

// DeepseekV3MoEToA2AAdapter: T=2048 tokens, H=1024, E=8, I=1408, top-2.
// fp32 I/O; weights pre-transposed+converted to bf16 [E][N][K] once (single
// packed-LDS kernel), bf16 MFMA GEMMs, non-atomic split-K down + 4-way combine.
#define T_TOK 2048
#define HDIM  1024
#define NEXP  8
#define IDIM  1408

#define BM 128
#define BN 64
#define BK 32
#define KPAD 40     // bf16 elems; 80 B rows, 16B-aligned, conflict-free frag reads
#define MT_SLOTS 16
#define GU_NT 22    // IDIM / BN
#define DN_NT 16    // HDIM / BN
#define DK_HALF 704 // IDIM / 2 (split-K for down)

typedef __attribute__((ext_vector_type(8))) short bf16x8;
typedef __attribute__((ext_vector_type(4))) float f32x4;

static __device__ __forceinline__ unsigned short f2bf(float f) {
    union { float f; unsigned u; } a; a.f = f;
    return (unsigned short)((a.u + 0x7fffu + ((a.u >> 16) & 1u)) >> 16);
}
static __device__ __forceinline__ unsigned pack2bf(float lo, float hi) {
    return (unsigned)f2bf(lo) | ((unsigned)f2bf(hi) << 16);
}

// ------------------------------------------------- router (+ x -> bf16) ----
__global__ __launch_bounds__(256) void router_kernel(
    const float* __restrict__ x,        // [T, H]
    const float* __restrict__ rw,       // [H, E]
    int*   __restrict__ counts,         // [E]
    int*   __restrict__ tok_list,       // [E][T]
    float* __restrict__ wgt_list,       // [E][T]
    int*   __restrict__ row_list,       // [E][T]  pair row id (2t / 2t+1)
    unsigned short* __restrict__ xb)    // [T, H] bf16 (fused conversion)
{
    const int wave = (blockIdx.x * blockDim.x + threadIdx.x) >> 6;
    const int lane = threadIdx.x & 63;
    if (wave >= T_TOK) return;
    const int t = wave;

    float xr[16];
    const float* xp = x + (size_t)t * HDIM;
#pragma unroll
    for (int i = 0; i < 16; ++i) xr[i] = xp[lane + 64 * i];

    // fused x conversion (x is being read anyway)
    unsigned short* xbp = xb + (size_t)t * HDIM;
#pragma unroll
    for (int i = 0; i < 16; ++i) xbp[lane + 64 * i] = f2bf(xr[i]);

    double logits[NEXP];
#pragma unroll
    for (int e = 0; e < NEXP; ++e) {
        double s = 0.0;
#pragma unroll
        for (int i = 0; i < 16; ++i) {
            const int j = lane + 64 * i;
            s += (double)xr[i] * (double)rw[j * NEXP + e];
        }
#pragma unroll
        for (int off = 32; off > 0; off >>= 1)
            s += __shfl_down(s, off, 64);
        logits[e] = s;
    }

    if (lane == 0) {
        int e1 = 0;
        for (int e = 1; e < NEXP; ++e) if (logits[e] > logits[e1]) e1 = e;
        int e2 = -1;
        for (int e = 0; e < NEXP; ++e) {
            if (e == e1) continue;
            if (e2 < 0 || logits[e] > logits[e2]) e2 = e;
        }
        const double w1 = 1.0 / (1.0 + exp(logits[e2] - logits[e1]));
        const double w2 = 1.0 - w1;
        int p1 = atomicAdd(&counts[e1], 1);
        tok_list[e1 * T_TOK + p1] = t;
        wgt_list[e1 * T_TOK + p1] = (float)w1;
        row_list[e1 * T_TOK + p1] = 2 * t;
        int p2 = atomicAdd(&counts[e2], 1);
        tok_list[e2 * T_TOK + p2] = t;
        wgt_list[e2 * T_TOK + p2] = (float)w2;
        row_list[e2 * T_TOK + p2] = 2 * t + 1;
    }
}

// ------------------------------- weight convert+transpose, all 3 tensors ----
// fp32 [E][K][N] -> bf16 [E][N][K], 64x64 tiles, packed u32 LDS writes.
// grid = (22, 16, 24): z<8 gate (K=1024,N=1408), z<16 up, else down (K=1408,N=1024).
__global__ __launch_bounds__(256) void wtrans_all_kernel(
    const float* __restrict__ gw, const float* __restrict__ uw,
    const float* __restrict__ dw,
    unsigned short* __restrict__ gwt, unsigned short* __restrict__ uwt,
    unsigned short* __restrict__ dwt)
{
    const int z = blockIdx.z;
    const float* src; unsigned short* dst; int K, N, k0, n0;
    if (z < 16) {
        K = HDIM; N = IDIM;
        const int e = z & 7;
        src = (z < 8 ? gw : uw) + (size_t)e * K * N;
        dst = (z < 8 ? gwt : uwt) + (size_t)e * (size_t)N * K;
        k0 = blockIdx.y * 64;      // 16 k-tiles
        n0 = blockIdx.x * 64;      // 22 n-tiles
    } else {
        K = IDIM; N = HDIM;
        const int e = z - 16;
        src = dw + (size_t)e * K * N;
        dst = dwt + (size_t)e * (size_t)N * K;
        k0 = blockIdx.x * 64;      // 22 k-tiles
        n0 = blockIdx.y * 64;      // 16 n-tiles
    }

    __shared__ unsigned short tile[64][72];   // [n][k]; row = 36 u32, aligned
    unsigned* tile32 = (unsigned*)&tile[0][0];
    const int t = threadIdx.x;

    // load + pack: thread covers k rows {2rp, 2rp+1} (+32 per pass), 4 n cols
    const int c4 = (t & 15) * 4;
    const int rp = t >> 4;                    // 0..15
#pragma unroll
    for (int p = 0; p < 2; ++p) {
        const int r = 2 * rp + 32 * p;
        const float4 va = *(const float4*)(src + (size_t)(k0 + r) * N + n0 + c4);
        const float4 vb = *(const float4*)(src + (size_t)(k0 + r + 1) * N + n0 + c4);
        const float* fa = (const float*)&va;
        const float* fb = (const float*)&vb;
        const int kk = rp + 16 * p;           // u32 index along k
#pragma unroll
        for (int i = 0; i < 4; ++i)
            tile32[(c4 + i) * 36 + kk] = pack2bf(fa[i], fb[i]);
    }
    __syncthreads();

    // store: 4 threads/row, 2x16B chunks each (contiguous along K)
    const int n   = t >> 2;
    const int ch0 = (t & 3) * 2;
#pragma unroll
    for (int q = 0; q < 2; ++q) {
        const int ch = ch0 + q;
        const uint4 v = *(const uint4*)&tile[n][ch * 8];
        *(uint4*)(dst + (size_t)(n0 + n) * K + k0 + ch * 8) = v;
    }
}

// -------------------------------------------------- fused gate+up GEMM -----
__global__ __launch_bounds__(256) void gateup_kernel(
    const unsigned short* __restrict__ xb,    // [T,H] bf16
    const unsigned short* __restrict__ gwt,   // [E][I][H] bf16
    const unsigned short* __restrict__ uwt,   // [E][I][H] bf16
    const float* __restrict__ gb, const float* __restrict__ ub,
    const int* __restrict__ counts,
    const int* __restrict__ tok_list,
    const int* __restrict__ row_list,
    unsigned short* __restrict__ act)         // [2T, IDIM] bf16
{
    const int flat = blockIdx.x;
    const int xcd  = flat & 7;
    const int q    = flat >> 3;
    const int mt   = q & 15;
    const int slot = q >> 4;
    const int P    = slot * 8 + xcd;   // 0..175 = (e, nt), fixed XCD per (e,nt)
    const int e    = P / GU_NT;
    const int nt   = P % GU_NT;
    const int n_e  = counts[e];
    const int m0   = mt * BM;
    if (m0 >= n_e) return;
    const int n0 = nt * BN;

    const unsigned short* gwp = gwt + (size_t)e * IDIM * HDIM;
    const unsigned short* uwp = uwt + (size_t)e * IDIM * HDIM;
    const float* gbp = gb + (size_t)e * IDIM;
    const float* ubp = ub + (size_t)e * IDIM;

    __shared__ unsigned short As[BM][KPAD];
    __shared__ unsigned short Bg[BN][KPAD];
    __shared__ unsigned short Bu[BN][KPAD];
    __shared__ int gr_lds[BM];
    __shared__ int or_lds[BM];

    const int tid = threadIdx.x;
    const int base = e * T_TOK;
    if (tid < BM) {
        const int m = m0 + tid;
        int g = -1, o = -1;
        if (m < n_e) { g = tok_list[base + m]; o = row_list[base + m]; }
        gr_lds[tid] = g; or_lds[tid] = o;
    }
    __syncthreads();

    const int ar = tid >> 1;
    const int ac = (tid & 1) * 16;
    const int arow = gr_lds[ar];
    const unsigned short* ap = xb + (size_t)(arow < 0 ? 0 : arow) * HDIM;
    const int u   = tid & 127;
    const int brow = u >> 1;
    const int bch  = (u & 1) * 16;
    const unsigned short* bsrc =
        ((tid >> 7) ? uwp : gwp) + (size_t)(n0 + brow) * HDIM + bch;
    unsigned short* Bdst =
        ((tid >> 7) ? &Bu[0][0] : &Bg[0][0]) + brow * KPAD + bch;

    const int wv = tid >> 6, lane = tid & 63;
    const int wm = (wv & 1) * 64, wn = (wv >> 1) * 32;
    const int l16 = lane & 15, quad = lane >> 4;

    f32x4 accg[4][2], accu[4][2];
    const f32x4 zero = {0.0f, 0.0f, 0.0f, 0.0f};
#pragma unroll
    for (int i = 0; i < 4; ++i)
#pragma unroll
        for (int j = 0; j < 2; ++j) { accg[i][j] = zero; accu[i][j] = zero; }

    uint4 PA0 = {0,0,0,0}, PA1 = {0,0,0,0}, PB0, PB1;
    if (arow >= 0) {
        PA0 = *(const uint4*)(ap + ac);
        PA1 = *(const uint4*)(ap + ac + 8);
    }
    PB0 = *(const uint4*)(bsrc);
    PB1 = *(const uint4*)(bsrc + 8);

    for (int k0 = 0; k0 < HDIM; k0 += BK) {
        __syncthreads();
        *(uint4*)&As[ar][ac]       = PA0;
        *(uint4*)&As[ar][ac + 8]   = PA1;
        *(uint4*)(Bdst)            = PB0;
        *(uint4*)(Bdst + 8)        = PB1;
        __syncthreads();

        const int kn = k0 + BK;
        if (kn < HDIM) {
            if (arow >= 0) {
                PA0 = *(const uint4*)(ap + kn + ac);
                PA1 = *(const uint4*)(ap + kn + ac + 8);
            }
            PB0 = *(const uint4*)(bsrc + kn);
            PB1 = *(const uint4*)(bsrc + kn + 8);
        }

        bf16x8 af[4], bgf[2], buf[2];
#pragma unroll
        for (int i = 0; i < 4; ++i)
            af[i] = *(const bf16x8*)&As[wm + i * 16 + l16][quad * 8];
#pragma unroll
        for (int j = 0; j < 2; ++j) {
            bgf[j] = *(const bf16x8*)&Bg[wn + j * 16 + l16][quad * 8];
            buf[j] = *(const bf16x8*)&Bu[wn + j * 16 + l16][quad * 8];
        }
#pragma unroll
        for (int i = 0; i < 4; ++i)
#pragma unroll
            for (int j = 0; j < 2; ++j) {
                accg[i][j] = __builtin_amdgcn_mfma_f32_16x16x32_bf16(
                    af[i], bgf[j], accg[i][j], 0, 0, 0);
                accu[i][j] = __builtin_amdgcn_mfma_f32_16x16x32_bf16(
                    af[i], buf[j], accu[i][j], 0, 0, 0);
            }
    }

    // epilogue: silu(g)*u -> bf16 act
#pragma unroll
    for (int j = 0; j < 2; ++j) {
        const int nl = n0 + wn + j * 16 + l16;
        const float gbv = gbp[nl];
        const float ubv = ubp[nl];
#pragma unroll
        for (int i = 0; i < 4; ++i) {
#pragma unroll
            for (int ii = 0; ii < 4; ++ii) {
                const int ml = wm + i * 16 + quad * 4 + ii;
                const int orow = or_lds[ml];
                if (orow >= 0) {
                    const float g = accg[i][j][ii] + gbv;
                    const float uu = accu[i][j][ii] + ubv;
                    act[(size_t)orow * IDIM + nl] =
                        f2bf(g * uu / (1.0f + __expf(-g)));
                }
            }
        }
    }
}

// ------------------------------------------------------- down-proj GEMM ----
// Split-K=2, NON-ATOMIC: slice sk writes plain stores into y2 + sk*(2T*H).
// Every pair-row is owned by exactly one block per slice -> no init needed.
__global__ __launch_bounds__(256) void down_kernel(
    const unsigned short* __restrict__ act,   // [2T, IDIM] bf16
    const unsigned short* __restrict__ dwt,   // [E][H][I] bf16
    const float* __restrict__ db,
    const int* __restrict__ counts,
    const float* __restrict__ wgt_list,
    const int* __restrict__ row_list,
    float* __restrict__ y2)                   // [2][2T, HDIM] fp32
{
    const int flat = blockIdx.x;
    const int xcd  = flat & 7;
    const int q    = flat >> 3;
    const int mt   = q & 15;
    const int slot = q >> 4;
    const int P    = slot * 8 + xcd;   // 0..255 = (sk, e, nt)
    const int sk   = P & 1;
    const int en   = P >> 1;
    const int e    = en >> 4;
    const int nt   = en & 15;
    const int n_e  = counts[e];
    const int m0   = mt * BM;
    if (m0 >= n_e) return;
    const int n0 = nt * BN;
    const int ks = sk * DK_HALF;
    float* y2s = y2 + (size_t)sk * 2 * T_TOK * HDIM;

    const unsigned short* dwp = dwt + (size_t)e * HDIM * IDIM;
    const float* dbp = db + (size_t)e * HDIM;

    __shared__ unsigned short As[BM][KPAD];
    __shared__ unsigned short Bs[BN][KPAD];
    __shared__ int   r_lds[BM];
    __shared__ float w_lds[BM];

    const int tid = threadIdx.x;
    const int base = e * T_TOK;
    if (tid < BM) {
        const int m = m0 + tid;
        int r = -1; float w = 0.0f;
        if (m < n_e) { r = row_list[base + m]; w = wgt_list[base + m]; }
        r_lds[tid] = r; w_lds[tid] = w;
    }
    __syncthreads();

    const int ar = tid >> 1;
    const int ac = (tid & 1) * 16;
    const int arow = r_lds[ar];
    const unsigned short* ap = act + (size_t)(arow < 0 ? 0 : arow) * IDIM + ks;
    const int brow = tid >> 2;
    const int bch  = (tid & 3) * 8;
    const unsigned short* bsrc = dwp + (size_t)(n0 + brow) * IDIM + ks + bch;
    unsigned short* Bdst = &Bs[0][0] + brow * KPAD + bch;

    const int wv = tid >> 6, lane = tid & 63;
    const int wm = (wv & 1) * 64, wn = (wv >> 1) * 32;
    const int l16 = lane & 15, quad = lane >> 4;

    f32x4 acc[4][2];
    const f32x4 zero = {0.0f, 0.0f, 0.0f, 0.0f};
#pragma unroll
    for (int i = 0; i < 4; ++i)
#pragma unroll
        for (int j = 0; j < 2; ++j) acc[i][j] = zero;

    uint4 PA0 = {0,0,0,0}, PA1 = {0,0,0,0}, PB;
    if (arow >= 0) {
        PA0 = *(const uint4*)(ap + ac);
        PA1 = *(const uint4*)(ap + ac + 8);
    }
    PB = *(const uint4*)(bsrc);

    for (int k0 = 0; k0 < DK_HALF; k0 += BK) {
        __syncthreads();
        *(uint4*)&As[ar][ac]     = PA0;
        *(uint4*)&As[ar][ac + 8] = PA1;
        *(uint4*)(Bdst)          = PB;
        __syncthreads();

        const int kn = k0 + BK;
        if (kn < DK_HALF) {
            if (arow >= 0) {
                PA0 = *(const uint4*)(ap + kn + ac);
                PA1 = *(const uint4*)(ap + kn + ac + 8);
            }
            PB = *(const uint4*)(bsrc + kn);
        }

        bf16x8 af[4], bfr[2];
#pragma unroll
        for (int i = 0; i < 4; ++i)
            af[i] = *(const bf16x8*)&As[wm + i * 16 + l16][quad * 8];
#pragma unroll
        for (int j = 0; j < 2; ++j)
            bfr[j] = *(const bf16x8*)&Bs[wn + j * 16 + l16][quad * 8];
#pragma unroll
        for (int i = 0; i < 4; ++i)
#pragma unroll
            for (int j = 0; j < 2; ++j)
                acc[i][j] = __builtin_amdgcn_mfma_f32_16x16x32_bf16(
                    af[i], bfr[j], acc[i][j], 0, 0, 0);
    }

#pragma unroll
    for (int j = 0; j < 2; ++j) {
        const int nl = n0 + wn + j * 16 + l16;
        const float bv = (sk == 0) ? dbp[nl] : 0.0f;
#pragma unroll
        for (int i = 0; i < 4; ++i) {
#pragma unroll
            for (int ii = 0; ii < 4; ++ii) {
                const int ml = wm + i * 16 + quad * 4 + ii;
                const int rr = r_lds[ml];
                if (rr >= 0)
                    y2s[(size_t)rr * HDIM + nl] = w_lds[ml] * (acc[i][j][ii] + bv);
            }
        }
    }
}

// --------------------------------------------------------------- combine ----
// out[t][h] = y2a[2t] + y2a[2t+1] + y2b[2t] + y2b[2t+1]
__global__ __launch_bounds__(256) void combine_kernel(
    const float* __restrict__ y2, float* __restrict__ out)
{
    const int idx = (blockIdx.x * 256 + threadIdx.x) * 4;   // < T*H
    const int t = idx >> 10;           // HDIM == 1024
    const int h = idx & 1023;
    const float* y2b = y2 + (size_t)2 * T_TOK * HDIM;
    const float4 a0 = *(const float4*)(y2  + ((size_t)2 * t) * HDIM + h);
    const float4 a1 = *(const float4*)(y2  + ((size_t)2 * t + 1) * HDIM + h);
    const float4 b0 = *(const float4*)(y2b + ((size_t)2 * t) * HDIM + h);
    const float4 b1 = *(const float4*)(y2b + ((size_t)2 * t + 1) * HDIM + h);
    float4 o;
    o.x = a0.x + a1.x + b0.x + b1.x;
    o.y = a0.y + a1.y + b0.y + b1.y;
    o.z = a0.z + a1.z + b0.z + b1.z;
    o.w = a0.w + a1.w + b0.w + b1.w;
    *(float4*)(out + idx) = o;
}

// ---------------------------------------------------------------- launch ----
extern "C" void kernel_launch(void* const* d_in, const int* in_sizes, int n_in,
                              void* d_out, int out_size, void* d_ws, size_t ws_size,
                              hipStream_t stream)
{
    const float* x      = (const float*)d_in[0];
    const float* rw     = (const float*)d_in[1];
    const float* gate_w = (const float*)d_in[2];
    const float* up_w   = (const float*)d_in[3];
    const float* down_w = (const float*)d_in[4];
    const float* gate_b = (const float*)d_in[5];
    const float* up_b   = (const float*)d_in[6];
    const float* down_b = (const float*)d_in[7];
    float* out = (float*)d_out;

    // workspace layout (~85 MB; y2[2 slices, 32 MB] aliases gwt+uwt,
    // which are dead after gateup)
    char* ws = (char*)d_ws;
    size_t off = 0;
    int*   counts   = (int*)(ws + off);  off += 256;
    int*   tok_list = (int*)(ws + off);  off += 65536;
    float* wgt_list = (float*)(ws + off); off += 65536;
    int*   row_list = (int*)(ws + off);  off += 65536;
    unsigned short* x_bf = (unsigned short*)(ws + off); off += (size_t)T_TOK * HDIM * 2;       // 4 MB
    unsigned short* act  = (unsigned short*)(ws + off); off += (size_t)2 * T_TOK * IDIM * 2;   // 11.5 MB
    unsigned short* dwt  = (unsigned short*)(ws + off); off += (size_t)NEXP * IDIM * HDIM * 2; // 23 MB
    unsigned short* gwt  = (unsigned short*)(ws + off); off += (size_t)NEXP * IDIM * HDIM * 2; // 23 MB
    unsigned short* uwt  = (unsigned short*)(ws + off);                                        // 23 MB
    float* y2 = (float*)gwt;   // 2 x 16 MB slices, reused after gateup

    (void)hipMemsetAsync(counts, 0, 256, stream);

    wtrans_all_kernel<<<dim3(22, 16, 24), 256, 0, stream>>>(
        gate_w, up_w, down_w, gwt, uwt, dwt);

    router_kernel<<<T_TOK / 4, 256, 0, stream>>>(x, rw, counts, tok_list,
                                                 wgt_list, row_list, x_bf);

    gateup_kernel<<<8 * GU_NT * MT_SLOTS, 256, 0, stream>>>(
        x_bf, gwt, uwt, gate_b, up_b, counts, tok_list, row_list, act);

    down_kernel<<<2 * 8 * DN_NT * MT_SLOTS, 256, 0, stream>>>(
        act, dwt, down_b, counts, wgt_list, row_list, y2);

    combine_kernel<<<(T_TOK * HDIM / 4) / 256, 256, 0, stream>>>(y2, out);
}